// Round 10
// baseline (192.601 us; speedup 1.0000x reference)
//
#include <hip/hip_runtime.h>

// Problem constants
#define ND 2048
#define NM 512
#define DIN 256
#define OC 128
#define NTOT (ND + NM)
#define NE (NM + 1)   // 513 slots per hyperedge

// Workspace (float offsets). Total = 7680 + 2560*128 = 335,360 floats = 1.34 MB.
#define WS_MEANC 0
#define WS_MEANM 256
#define WS_WE    512
#define WS_DIA   768
#define WS_MED   896
#define WS_AHE   1024
#define WS_ANODE 3072
#define WS_CD    5632
#define WS_XLIN  7680   // [2560*128]; disease rows overwritten by e in kD

__device__ __forceinline__ float lrelu(float x) { return x > 0.f ? x : 0.2f * x; }

// ---------------------------------------------------------------------------
// kA: column means of c_emb / m_emb, and w_e[i] = sum_o W_gat[o,i]*att[OC+o]
__global__ void kA(const float* __restrict__ c_emb,
                   const float* __restrict__ m_emb,
                   const float* __restrict__ W_gat,
                   const float* __restrict__ att,
                   float* __restrict__ ws) {
    const int i = blockIdx.x;
    const int t = threadIdx.x;
    float sc = 0.f, sm = 0.f, sw = 0.f;
    for (int r = t; r < ND; r += 256) sc += c_emb[(size_t)r * DIN + i];
    for (int r = t; r < NM; r += 256) sm += m_emb[(size_t)r * DIN + i];
    if (t < OC) sw = W_gat[(size_t)t * DIN + i] * att[OC + t];
    __shared__ float s1[256], s2[256], s3[256];
    s1[t] = sc; s2[t] = sm; s3[t] = sw;
    __syncthreads();
    for (int s = 128; s > 0; s >>= 1) {
        if (t < s) { s1[t] += s1[t + s]; s2[t] += s2[t + s]; s3[t] += s3[t + s]; }
        __syncthreads();
    }
    if (t == 0) {
        ws[WS_MEANC + i] = s1[0] * (1.f / ND);
        ws[WS_MEANM + i] = s2[0] * (1.f / NM);
        ws[WS_WE + i]    = s3[0];
    }
}

// ---------------------------------------------------------------------------
// kB: block 0 -> dia/med vectors = mean @ W_conv.T + b_conv;
//     blocks 1..ND -> a_he[d] = he_attr[d,:] . w_e
__global__ void kB(const float* __restrict__ W_conv,
                   const float* __restrict__ b_conv,
                   const float* __restrict__ he_attr,
                   float* __restrict__ ws) {
    if (blockIdx.x == 0) {
        const int o = threadIdx.x;
        if (o < OC) {
            const float* mc = ws + WS_MEANC;
            const float* mm = ws + WS_MEANM;
            const float* wr = W_conv + (size_t)o * DIN;
            float a = 0.f, b = 0.f;
            for (int i = 0; i < DIN; ++i) {
                float w = wr[i];
                a = fmaf(mc[i], w, a);
                b = fmaf(mm[i], w, b);
            }
            float bc = b_conv[o];
            ws[WS_DIA + o] = a + bc;
            ws[WS_MED + o] = b + bc;
        }
    } else {
        const int d = blockIdx.x - 1;
        const int t = threadIdx.x;
        float p = he_attr[(size_t)d * DIN + t] * ws[WS_WE + t];
        __shared__ float s[256];
        s[t] = p;
        __syncthreads();
        for (int st = 128; st > 0; st >>= 1) {
            if (t < st) s[t] += s[t + st];
            __syncthreads();
        }
        if (t == 0) ws[WS_AHE + d] = s[0];
    }
}

// ---------------------------------------------------------------------------
// kC: x_lin[d,:] = comb[d,:] @ W_gat.T ; a_node[d] = x_lin[d,:] . att[:OC]
__global__ void kC(const float* __restrict__ c_emb,
                   const float* __restrict__ m_emb,
                   const float* __restrict__ W_gat,
                   const float* __restrict__ att,
                   float* __restrict__ ws) {
    const int d = blockIdx.x;
    const int t = threadIdx.x;  // 0..127
    __shared__ float row[DIN];
    const float* src = (d < ND) ? (c_emb + (size_t)d * DIN)
                                : (m_emb + (size_t)(d - ND) * DIN);
    float2 u = ((const float2*)src)[t];
    row[2 * t]     = u.x;
    row[2 * t + 1] = u.y;
    __syncthreads();
    const float4* wr = (const float4*)(W_gat + (size_t)t * DIN);
    float acc = 0.f;
#pragma unroll
    for (int v = 0; v < DIN / 4; ++v) {
        float4 w = wr[v];
        const int ib = v * 4;
        acc = fmaf(row[ib + 0], w.x, acc);
        acc = fmaf(row[ib + 1], w.y, acc);
        acc = fmaf(row[ib + 2], w.z, acc);
        acc = fmaf(row[ib + 3], w.w, acc);
    }
    ws[WS_XLIN + (size_t)d * OC + t] = acc;
    __shared__ float s[OC];
    s[t] = acc * att[t];
    __syncthreads();
    for (int st = 64; st > 0; st >>= 1) {
        if (t < st) s[t] += s[t + st];
        __syncthreads();
    }
    if (t == 0) ws[WS_ANODE + d] = s[0];
}

// ---------------------------------------------------------------------------
// kD: one hyperedge per block (grid ND, 256 threads): softmax, e, disease row.
// Documented placement: cols 0..127 = dm part, cols 128..255 = dia_nf.
__global__ void kD(const float* __restrict__ b_gat,
                   float* __restrict__ ws,
                   float* __restrict__ out) {
    const int d = blockIdx.x;
    const int t = threadIdx.x;  // 0..255
    __shared__ float sA[NE];
    __shared__ float red[256];
    __shared__ float ec[OC];
    const float* a_node = ws + WS_ANODE;
    const float ahe = ws[WS_AHE + d];

    float lmax = -3.4e38f;
    for (int j = t; j < NE; j += 256) {
        int node = (j == 0) ? d : (ND + j - 1);
        float l = lrelu(a_node[node] + ahe);
        sA[j] = l;
        lmax = fmaxf(lmax, l);
    }
    red[t] = lmax;
    __syncthreads();
    for (int s = 128; s > 0; s >>= 1) {
        if (t < s) red[t] = fmaxf(red[t], red[t + s]);
        __syncthreads();
    }
    const float M = red[0];
    __syncthreads();
    float lsum = 0.f;
    for (int j = t; j < NE; j += 256) {
        float z = __expf(sA[j] - M);
        sA[j] = z;
        lsum += z;
    }
    red[t] = lsum;
    __syncthreads();
    for (int s = 128; s > 0; s >>= 1) {
        if (t < s) red[t] += red[t + s];
        __syncthreads();
    }
    const float S = red[0];
    const float inv = 1.f / S;
    if (t == 0) ws[WS_CD + d] = M + __logf(S);

    const int o = t & (OC - 1);
    const int h = t >> 7;
    float acc = 0.f;
    const float* xlin = ws + WS_XLIN;
    for (int j = 1 + h * 256; j < 1 + h * 256 + 256; ++j) {
        acc = fmaf(sA[j], xlin[(size_t)(ND + j - 1) * OC + o], acc);
    }
    if (h == 1) ec[o] = acc;
    __syncthreads();
    if (h == 0) {
        const float a0 = sA[0] * inv;
        const float xown = xlin[(size_t)d * OC + o];
        float ev = (fmaf(sA[0], xown, acc + ec[o])) * inv * (1.0f / NE);
        ws[WS_XLIN + (size_t)d * OC + o] = ev;  // e in-place
        out[(size_t)d * 2 * OC + o]      = fmaf(a0, ev, b_gat[o]);  // dm part
        out[(size_t)d * 2 * OC + OC + o] = ws[WS_DIA + o];          // dia_nf
    }
}

// ---------------------------------------------------------------------------
// kE: 4 medicines per block (grid NM/4, 256 threads)
__global__ void kE(const float* __restrict__ b_gat,
                   const float* __restrict__ ws,
                   float* __restrict__ out) {
    const int t = threadIdx.x;
    const int m0 = blockIdx.x * 4;
    __shared__ float sZ[4][ND];   // 32 KB
    __shared__ float ec[4][OC];
    const float* a_node = ws + WS_ANODE;
    const float* a_he   = ws + WS_AHE;
    const float* C      = ws + WS_CD;
    float anm[4];
#pragma unroll
    for (int k = 0; k < 4; ++k) anm[k] = a_node[ND + m0 + k];
    for (int d = t; d < ND; d += 256) {
        const float ahe = a_he[d];
        const float cd  = C[d];
#pragma unroll
        for (int k = 0; k < 4; ++k) sZ[k][d] = __expf(lrelu(anm[k] + ahe) - cd);
    }
    __syncthreads();

    const int o = t & (OC - 1);
    const int h = t >> 7;
    const float* e = ws + WS_XLIN;
    float acc[4] = {0.f, 0.f, 0.f, 0.f};
    for (int d = h * (ND / 2); d < (h + 1) * (ND / 2); ++d) {
        const float ev = e[(size_t)d * OC + o];
#pragma unroll
        for (int k = 0; k < 4; ++k) acc[k] = fmaf(sZ[k][d], ev, acc[k]);
    }
    if (h == 1) {
#pragma unroll
        for (int k = 0; k < 4; ++k) ec[k][o] = acc[k];
    }
    __syncthreads();
    if (h == 0) {
        const float bg = b_gat[o];
        const float mv = ws[WS_MED + o];
#pragma unroll
        for (int k = 0; k < 4; ++k) {
            const int m = m0 + k;
            float v = fmaf(acc[k] + ec[k][o], (1.0f / ND), bg);
            out[(size_t)(ND + m) * 2 * OC + o]      = v;   // dm part
            out[(size_t)(ND + m) * 2 * OC + OC + o] = mv;  // med_nf
        }
    }
}

extern "C" void kernel_launch(void* const* d_in, const int* in_sizes, int n_in,
                              void* d_out, int out_size, void* d_ws, size_t ws_size,
                              hipStream_t stream) {
    // f32 inputs, documented dict-order indexing, FLOAT32 output.
    const float* c_emb   = (const float*)d_in[2];
    const float* m_emb   = (const float*)d_in[3];
    const float* W_conv  = (const float*)d_in[4];
    const float* b_conv  = (const float*)d_in[5];
    const float* W_gat   = (const float*)d_in[6];
    const float* att     = (const float*)d_in[7];
    const float* b_gat   = (const float*)d_in[8];
    const float* he_attr = (const float*)d_in[9];
    float* ws  = (float*)d_ws;
    float* out = (float*)d_out;  // FLOAT32 output (reference returns jnp.float32)

    hipLaunchKernelGGL(kA, dim3(DIN),    dim3(256), 0, stream, c_emb, m_emb, W_gat, att, ws);
    hipLaunchKernelGGL(kC, dim3(NTOT),   dim3(OC),  0, stream, c_emb, m_emb, W_gat, att, ws);
    hipLaunchKernelGGL(kB, dim3(ND + 1), dim3(256), 0, stream, W_conv, b_conv, he_attr, ws);
    hipLaunchKernelGGL(kD, dim3(ND),     dim3(256), 0, stream, b_gat, ws, out);
    hipLaunchKernelGGL(kE, dim3(NM / 4), dim3(256), 0, stream, b_gat, ws, out);
}

// Round 11
// 152.641 us; speedup vs baseline: 1.2618x; 1.2618x over previous
//
#include <hip/hip_runtime.h>

// Problem constants
#define ND 2048
#define NM 512
#define DIN 256
#define OC 128
#define NTOT (ND + NM)
#define NE (NM + 1)   // 513 slots per hyperedge

// Workspace (float offsets). Total 881,152 floats = 3.52 MB.
#define WS_MEANC 0
#define WS_MEANM 256
#define WS_WE    512
#define WS_DIA   768
#define WS_MED   896
#define WS_AHE   1024
#define WS_ANODE 3072
#define WS_CD    5632
#define WS_XLIN  7680                      // [2560*128]; disease rows overwritten by e in kD
#define WS_PART1 (WS_XLIN + NTOT * OC)     // [84*256] kA1 partials
#define WS_PART2 (WS_PART1 + 84 * 256)     // [32*8*16*128] kE1 partials (2 MB)

__device__ __forceinline__ float lrelu(float x) { return x > 0.f ? x : 0.2f * x; }

// ---------------------------------------------------------------------------
// kA1: coalesced partial sums. Blocks 0..63: 32 rows of c_emb each.
// Blocks 64..79: 32 rows of m_emb. Blocks 80..83: 32 rows of W_gat*att[OC+o].
// 256 threads; thread t owns column t.
__global__ void kA1(const float* __restrict__ c_emb, const float* __restrict__ m_emb,
                    const float* __restrict__ W_gat, const float* __restrict__ att,
                    float* __restrict__ ws) {
    const int b = blockIdx.x;
    const int t = threadIdx.x;
    float acc = 0.f;
    if (b < 64) {
        const float* src = c_emb + (size_t)b * 32 * DIN;
        for (int r = 0; r < 32; ++r) acc += src[r * DIN + t];
    } else if (b < 80) {
        const float* src = m_emb + (size_t)(b - 64) * 32 * DIN;
        for (int r = 0; r < 32; ++r) acc += src[r * DIN + t];
    } else {
        const int o0 = (b - 80) * 32;
        for (int r = 0; r < 32; ++r)
            acc += W_gat[(size_t)(o0 + r) * DIN + t] * att[OC + o0 + r];
    }
    ws[WS_PART1 + b * 256 + t] = acc;
}

// kA2: combine partials -> meanC, meanM, w_e. 1 block, 256 threads.
__global__ void kA2(float* __restrict__ ws) {
    const int t = threadIdx.x;
    const float* p = ws + WS_PART1;
    float sc = 0.f, sm = 0.f, sw = 0.f;
    for (int b = 0;  b < 64; ++b) sc += p[b * 256 + t];
    for (int b = 64; b < 80; ++b) sm += p[b * 256 + t];
    for (int b = 80; b < 84; ++b) sw += p[b * 256 + t];
    ws[WS_MEANC + t] = sc * (1.f / ND);
    ws[WS_MEANM + t] = sm * (1.f / NM);
    ws[WS_WE + t]    = sw;
}

// ---------------------------------------------------------------------------
// kB: block 0 -> dia/med vectors; blocks 1..ND -> a_he[d] (shfl-based reduce).
__global__ void kB(const float* __restrict__ W_conv, const float* __restrict__ b_conv,
                   const float* __restrict__ he_attr, float* __restrict__ ws) {
    if (blockIdx.x == 0) {
        const int o = threadIdx.x;
        if (o < OC) {
            const float* mc = ws + WS_MEANC;
            const float* mm = ws + WS_MEANM;
            const float* wr = W_conv + (size_t)o * DIN;
            float a = 0.f, b = 0.f;
            for (int i = 0; i < DIN; ++i) {
                float w = wr[i];
                a = fmaf(mc[i], w, a);
                b = fmaf(mm[i], w, b);
            }
            float bc = b_conv[o];
            ws[WS_DIA + o] = a + bc;
            ws[WS_MED + o] = b + bc;
        }
    } else {
        const int d = blockIdx.x - 1;
        const int t = threadIdx.x;
        float p = he_attr[(size_t)d * DIN + t] * ws[WS_WE + t];
        for (int m = 1; m < 64; m <<= 1) p += __shfl_xor(p, m, 64);
        __shared__ float s[4];
        if ((t & 63) == 0) s[t >> 6] = p;
        __syncthreads();
        if (t == 0) ws[WS_AHE + d] = s[0] + s[1] + s[2] + s[3];
    }
}

// ---------------------------------------------------------------------------
// kC: 4 rows per block (grid 640, 128 threads). W_gat row read once per 4 rows.
__global__ void kC(const float* __restrict__ c_emb, const float* __restrict__ m_emb,
                   const float* __restrict__ W_gat, const float* __restrict__ att,
                   float* __restrict__ ws) {
    const int d0 = blockIdx.x * 4;
    const int t = threadIdx.x;  // 0..127 (= output channel)
    __shared__ float row[4][DIN];
    for (int r = 0; r < 4; ++r) {
        const int d = d0 + r;
        const float* src = (d < ND) ? (c_emb + (size_t)d * DIN)
                                    : (m_emb + (size_t)(d - ND) * DIN);
        float2 u = ((const float2*)src)[t];
        row[r][2 * t] = u.x;
        row[r][2 * t + 1] = u.y;
    }
    __syncthreads();
    const float4* wr = (const float4*)(W_gat + (size_t)t * DIN);
    float a0 = 0.f, a1 = 0.f, a2 = 0.f, a3 = 0.f;
#pragma unroll 8
    for (int v = 0; v < DIN / 4; ++v) {
        float4 w = wr[v];
        const int ib = v * 4;
        a0 = fmaf(row[0][ib], w.x, a0); a0 = fmaf(row[0][ib+1], w.y, a0);
        a0 = fmaf(row[0][ib+2], w.z, a0); a0 = fmaf(row[0][ib+3], w.w, a0);
        a1 = fmaf(row[1][ib], w.x, a1); a1 = fmaf(row[1][ib+1], w.y, a1);
        a1 = fmaf(row[1][ib+2], w.z, a1); a1 = fmaf(row[1][ib+3], w.w, a1);
        a2 = fmaf(row[2][ib], w.x, a2); a2 = fmaf(row[2][ib+1], w.y, a2);
        a2 = fmaf(row[2][ib+2], w.z, a2); a2 = fmaf(row[2][ib+3], w.w, a2);
        a3 = fmaf(row[3][ib], w.x, a3); a3 = fmaf(row[3][ib+1], w.y, a3);
        a3 = fmaf(row[3][ib+2], w.z, a3); a3 = fmaf(row[3][ib+3], w.w, a3);
    }
    float* xl = ws + WS_XLIN + (size_t)d0 * OC;
    xl[0 * OC + t] = a0; xl[1 * OC + t] = a1; xl[2 * OC + t] = a2; xl[3 * OC + t] = a3;
    const float at = att[t];
    __shared__ float s[4][OC];
    s[0][t] = a0 * at; s[1][t] = a1 * at; s[2][t] = a2 * at; s[3][t] = a3 * at;
    __syncthreads();
    for (int st = 64; st > 0; st >>= 1) {
        if (t < st) {
#pragma unroll
            for (int r = 0; r < 4; ++r) s[r][t] += s[r][t + st];
        }
        __syncthreads();
    }
    if (t < 4) ws[WS_ANODE + d0 + t] = s[t][0];
}

// ---------------------------------------------------------------------------
// kD: 8 hyperedges per block (grid 256, 256 threads).
// Phase A: 8 parallel softmaxes via 32-lane shfl groups (group r = hyperedge d0+r).
// Phase B: 8x512x128 mini-GEMM vs Xm; e stored in-place; disease output rows.
#define DT 8
__global__ void kD(const float* __restrict__ b_gat, float* __restrict__ ws,
                   float* __restrict__ out) {
    const int d0 = blockIdx.x * DT;
    const int t = threadIdx.x;  // 0..255
    const int r = t >> 5, l = t & 31;
    __shared__ float zbuf[DT][NE];   // 16.4 KB: logits then z
    __shared__ float anm[NM];        // medicine a_node
    __shared__ float ec[DT][OC];
    __shared__ float sinv[DT];
    const float* a_node = ws + WS_ANODE;
    anm[t] = a_node[ND + t];
    anm[t + 256] = a_node[ND + t + 256];
    __syncthreads();
    {
        const int d = d0 + r;
        const float ahe = ws[WS_AHE + d];
        float lmax = -3.4e38f;
        for (int j = l; j < NE; j += 32) {
            float v = (j == 0) ? a_node[d] : anm[j - 1];
            float lg = lrelu(v + ahe);
            zbuf[r][j] = lg;
            lmax = fmaxf(lmax, lg);
        }
        for (int m = 1; m < 32; m <<= 1) lmax = fmaxf(lmax, __shfl_xor(lmax, m, 32));
        float ssum = 0.f;
        for (int j = l; j < NE; j += 32) {
            float z = __expf(zbuf[r][j] - lmax);
            zbuf[r][j] = z;
            ssum += z;
        }
        for (int m = 1; m < 32; m <<= 1) ssum += __shfl_xor(ssum, m, 32);
        if (l == 0) {
            sinv[r] = 1.f / ssum;
            ws[WS_CD + d] = lmax + __logf(ssum);
        }
    }
    __syncthreads();
    // Phase B
    const int o = t & (OC - 1);
    const int h = t >> 7;
    float acc[DT];
#pragma unroll
    for (int k = 0; k < DT; ++k) acc[k] = 0.f;
    const float* xm = ws + WS_XLIN + (size_t)ND * OC;
#pragma unroll 4
    for (int j = h * 256; j < h * 256 + 256; ++j) {
        float xv = xm[(size_t)j * OC + o];
#pragma unroll
        for (int k = 0; k < DT; ++k) acc[k] = fmaf(zbuf[k][j + 1], xv, acc[k]);
    }
    if (h == 1) {
#pragma unroll
        for (int k = 0; k < DT; ++k) ec[k][o] = acc[k];
    }
    __syncthreads();
    if (h == 0) {
        const float bg = b_gat[o];
        const float dv = ws[WS_DIA + o];
#pragma unroll
        for (int k = 0; k < DT; ++k) {
            const int d = d0 + k;
            const float inv = sinv[k];
            const float z0 = zbuf[k][0];
            const float xown = ws[WS_XLIN + (size_t)d * OC + o];
            float ev = fmaf(z0, xown, acc[k] + ec[k][o]) * inv * (1.f / NE);
            ws[WS_XLIN + (size_t)d * OC + o] = ev;       // e in-place
            out[(size_t)d * 2 * OC + o]      = fmaf(z0 * inv, ev, bg);
            out[(size_t)d * 2 * OC + OC + o] = dv;
        }
    }
}

// ---------------------------------------------------------------------------
// kE1: partial Z^T @ e. Grid (32 m-groups x 8 d-chunks), 256 threads.
// Block (g,c): 16 medicines (g*16..), 256 diseases (c*256..).
__global__ void kE1(float* __restrict__ ws) {
    const int g = blockIdx.x, c = blockIdx.y;
    const int t = threadIdx.x;
    __shared__ float zb[256][16];   // [dd][mi], 16 KB
    const float* a_node = ws + WS_ANODE;
    const float* ahe = ws + WS_AHE;
    const float* C = ws + WS_CD;
    for (int idx = t; idx < 4096; idx += 256) {
        const int mi = idx & 15, dd = idx >> 4;
        const int d = c * 256 + dd;
        zb[dd][mi] = __expf(lrelu(a_node[ND + g * 16 + mi] + ahe[d]) - C[d]);
    }
    __syncthreads();
    const int o = t & (OC - 1);
    const int h = t >> 7;
    float acc[16];
#pragma unroll
    for (int k = 0; k < 16; ++k) acc[k] = 0.f;
    const float* e = ws + WS_XLIN;
#pragma unroll 2
    for (int dd = h * 128; dd < h * 128 + 128; ++dd) {
        float ev = e[(size_t)(c * 256 + dd) * OC + o];
#pragma unroll
        for (int k = 0; k < 16; ++k) acc[k] = fmaf(zb[dd][k], ev, acc[k]);
    }
    __shared__ float ec[16][OC];    // 8 KB
    if (h == 1) {
#pragma unroll
        for (int k = 0; k < 16; ++k) ec[k][o] = acc[k];
    }
    __syncthreads();
    if (h == 0) {
        float* part = ws + WS_PART2 + (size_t)(g * 8 + c) * 16 * OC;
#pragma unroll
        for (int k = 0; k < 16; ++k) part[k * OC + o] = acc[k] + ec[k][o];
    }
}

// kE2: reduce 8 chunk-partials per medicine, add bias, write output rows.
// Grid NM (512), 128 threads.
__global__ void kE2(const float* __restrict__ b_gat, const float* __restrict__ ws,
                    float* __restrict__ out) {
    const int m = blockIdx.x;
    const int o = threadIdx.x;
    const int g = m >> 4, k = m & 15;
    const float* part = ws + WS_PART2;
    float s = 0.f;
#pragma unroll
    for (int c = 0; c < 8; ++c) s += part[((size_t)(g * 8 + c) * 16 + k) * OC + o];
    out[(size_t)(ND + m) * 2 * OC + o]      = fmaf(s, 1.f / ND, b_gat[o]);
    out[(size_t)(ND + m) * 2 * OC + OC + o] = ws[WS_MED + o];
}

extern "C" void kernel_launch(void* const* d_in, const int* in_sizes, int n_in,
                              void* d_out, int out_size, void* d_ws, size_t ws_size,
                              hipStream_t stream) {
    const float* c_emb   = (const float*)d_in[2];
    const float* m_emb   = (const float*)d_in[3];
    const float* W_conv  = (const float*)d_in[4];
    const float* b_conv  = (const float*)d_in[5];
    const float* W_gat   = (const float*)d_in[6];
    const float* att     = (const float*)d_in[7];
    const float* b_gat   = (const float*)d_in[8];
    const float* he_attr = (const float*)d_in[9];
    float* ws  = (float*)d_ws;
    float* out = (float*)d_out;  // float32 output

    hipLaunchKernelGGL(kA1, dim3(84),        dim3(256), 0, stream, c_emb, m_emb, W_gat, att, ws);
    hipLaunchKernelGGL(kA2, dim3(1),         dim3(256), 0, stream, ws);
    hipLaunchKernelGGL(kC,  dim3(NTOT / 4),  dim3(128), 0, stream, c_emb, m_emb, W_gat, att, ws);
    hipLaunchKernelGGL(kB,  dim3(ND + 1),    dim3(256), 0, stream, W_conv, b_conv, he_attr, ws);
    hipLaunchKernelGGL(kD,  dim3(ND / DT),   dim3(256), 0, stream, b_gat, ws, out);
    hipLaunchKernelGGL(kE1, dim3(32, 8),     dim3(256), 0, stream, ws);
    hipLaunchKernelGGL(kE2, dim3(NM),        dim3(128), 0, stream, b_gat, ws, out);
}